// Round 1
// baseline (238.493 us; speedup 1.0000x reference)
//
#include <hip/hip_runtime.h>
#include <math.h>

// (256, 4096, 33) f32 rows: [K, w1[0..31]]; K passes through; w1 gets
// 4x (31-step push-apart scan + clip). One thread per row, row in registers.
//
// R2 post-mortem: 128-thr bulk-sync blocks -> 83 us kernel at 2.5 TB/s with
// VALUBusy 24% / Occ 40% -> phase convoy: __syncthreads() compiles to a full
// s_waitcnt vmcnt(0) drain, so every block alternates {DMA burst | dead
// compute phase | store burst} and the memory pipe idles ~50% of the time.
// R3: persistent SINGLE-WAVE blocks (64 thr = 64 rows/tile, no barriers at
// all) with double-buffered LDS and counted-vmcnt software pipeline:
// issue DMA(t+1) -> s_waitcnt vmcnt(18) (tile t done; next tile's 9 DMAs +
// previous tile's 9 stores stay in flight) -> compute t -> store t.
// Per-wave VMEM counts are exact in a 1-wave block: 9 DMA + 9 stores/tile.
// Grid 2048 = 8 blocks/CU (2x8.4 KB LDS), fully resident, ~34 MB in flight.

#define THREADS 64
#define ROW 33
#define TROWS 64                  // rows per tile (= one wave)
#define FPT (TROWS * ROW)         // 2112 floats per tile (8448 B)
#define V4PT (FPT / 4)            // 528 float4 per tile
#define GRID 2048

typedef const __attribute__((address_space(1))) unsigned int* gas_p;
typedef __attribute__((address_space(3))) unsigned int* las_p;

// Global -> LDS direct DMA, 16 B per lane per round. 528 float4:
// 8 full rounds of 64 lanes + a 16-lane tail. LDS dest is the required
// wave-uniform base + lane*16 contiguous pattern. Exactly 9 VMEM instrs
// per wave (tail has nonzero exec in a 1-wave block -> always issued).
__device__ __forceinline__ void stage_tile(const float* __restrict__ gin,
                                           las_p s, int tid)
{
    gas_p g = (gas_p)gin;
#pragma unroll
    for (int j = 0; j < 8; ++j)
        __builtin_amdgcn_global_load_lds(g + (size_t)(tid + j * THREADS) * 4,
                                         s + (size_t)(tid + j * THREADS) * 4,
                                         16, 0, 0);
    if (tid < (V4PT - 8 * THREADS))   // 16-lane tail, 1 VMEM instr
        __builtin_amdgcn_global_load_lds(g + (size_t)(tid + 8 * THREADS) * 4,
                                         s + (size_t)(tid + 8 * THREADS) * 4,
                                         16, 0, 0);
}

__global__ __launch_bounds__(THREADS) void lsp_stability_kernel(
    const float* __restrict__ in, float* __restrict__ out, int tiles)
{
    __shared__ alignas(16) float smem[2][FPT];
    const int tid = threadIdx.x;
    const int bid = blockIdx.x;
    if (bid >= tiles) return;
    const int grid = (int)gridDim.x;
    const int nt = (tiles - bid + grid - 1) / grid;   // tiles for this block

    const float MIND = (float)(0.01 * M_PI / 33.0);   // RATE*pi/(ORDER+1)
    const float PI_F = (float)M_PI;
    const float HI = PI_F - MIND;

    // Prologue: DMA tile 0 into buf 0, don't wait.
    stage_tile(in + (size_t)bid * FPT, (las_p)&smem[0][0], tid);

    for (int t = 0; t < nt; ++t) {
        const size_t tile = (size_t)bid + (size_t)t * grid;
        const int cur = t & 1;

        // Issue next tile's DMA into the other buffer. That buffer held
        // tile t-1, whose store ds_reads completed before its
        // global_stores issued (program order, LDS alias-ordered).
        if (t + 1 < nt)
            stage_tile(in + (tile + grid) * FPT, (las_p)&smem[cur ^ 1][0], tid);

        // Wait for THIS tile's 9 DMAs only. Per-wave VMEM issue order:
        // [DMA(t)] [stores(t-1): 9] [DMA(t+1): 9] -> newer-than-DMA(t)
        // = 18 steady-state, 9 on first/last tile. Never vmcnt(0) in the
        // steady loop -> loads/stores stream across tiles.
        if (t > 0 && t + 1 < nt)
            asm volatile("s_waitcnt vmcnt(18)" ::: "memory");
        else if (t == 0 && t + 1 == nt)
            asm volatile("s_waitcnt vmcnt(0)" ::: "memory");
        else
            asm volatile("s_waitcnt vmcnt(9)" ::: "memory");

        // Each thread owns one row; w1 (32 elems) in registers.
        // LDS row stride 33 -> 2-way bank aliasing across wave64 (free).
        float w[32];
        float* row = &smem[cur][0] + tid * ROW;
#pragma unroll
        for (int k = 0; k < 32; ++k) w[k] = row[k + 1];

#pragma unroll
        for (int it = 0; it < 4; ++it) {
            float c = w[0];
#pragma unroll
            for (int k = 1; k < 32; ++k) {
                float nxt = w[k];
                float sft = 0.5f * fmaxf(MIND - (nxt - c), 0.0f);
                w[k - 1] = c - sft;   // 0.5*m exact (pow2 mul) -> fma-safe
                c = nxt + sft;
            }
            w[31] = c;
#pragma unroll
            for (int k = 0; k < 32; ++k)
                w[k] = fminf(fmaxf(w[k], MIND), HI);
        }

        // K (element 0) untouched in LDS; write back w1 only.
#pragma unroll
        for (int k = 0; k < 32; ++k) row[k + 1] = w[k];

        // Coalesced LDS -> global store: 8 rounds + 16-lane tail
        // = exactly 9 global_store_dwordx4 per wave. No barrier needed
        // (single wave; compiler orders ds_read -> lgkmcnt -> store).
        float4* out4 = (float4*)(out + tile * FPT);
        const float4* s4 = (const float4*)&smem[cur][0];
#pragma unroll
        for (int j = 0; j < 8; ++j)
            out4[tid + j * THREADS] = s4[tid + j * THREADS];
        if (tid < (V4PT - 8 * THREADS))
            out4[tid + 8 * THREADS] = s4[tid + 8 * THREADS];
    }
}

extern "C" void kernel_launch(void* const* d_in, const int* in_sizes, int n_in,
                              void* d_out, int out_size, void* d_ws, size_t ws_size,
                              hipStream_t stream) {
    const float* in = (const float*)d_in[0];
    float* out = (float*)d_out;
    // total = 256*4096*33 = 34,603,008 floats; 2112 per tile -> 16384 tiles.
    const int tiles = in_sizes[0] / FPT;
    const int blocks = tiles < GRID ? tiles : GRID;   // 2048 -> 8 tiles/block
    lsp_stability_kernel<<<blocks, THREADS, 0, stream>>>(in, out, tiles);
}